// Round 18
// baseline (196.796 us; speedup 1.0000x reference)
//
#include <hip/hip_runtime.h>

#define DEVFN __device__ __forceinline__

typedef __bf16 bf16x8 __attribute__((ext_vector_type(8)));
typedef float f32x4 __attribute__((ext_vector_type(4)));
typedef unsigned short u16;

// B=2, T=S=2048, D=1024, H=16, DH=64
// Scales folded into weights: Wq *= 0.125*log2(e), Wk *= 0.125  =>
// score_log2e = q'.k' + q'.L  ; softmax done in exp2 domain.
// Key axis of P and V permuted per 64-key tile by pi(k) = 4*(k&15) + (k>>4).

DEVFN u16 f2bf(float f) {
  unsigned u = __builtin_bit_cast(unsigned, f);
  u += 0x7FFFu + ((u >> 16) & 1u);
  return (u16)(u >> 16);
}

DEVFN f32x4 mfma16(bf16x8 a, bf16x8 b, f32x4 c) {
  return __builtin_amdgcn_mfma_f32_16x16x32_bf16(a, b, c, 0, 0, 0);
}

DEVFN void gl16(const u16* g, u16* l) {
  __builtin_amdgcn_global_load_lds(
      (const __attribute__((address_space(1))) unsigned int*)g,
      (__attribute__((address_space(3))) unsigned int*)l, 16, 0, 0);
}

// ---------------- LayerNorm: x[4096,1024] -> xn (f32, into d_out) + xn bf16 ----------------
__global__ __launch_bounds__(256) void ln_kernel(const float* __restrict__ x,
                                                 const float* __restrict__ gamma,
                                                 const float* __restrict__ beta,
                                                 float* __restrict__ xn,
                                                 u16* __restrict__ xnb) {
  int row = blockIdx.x;
  int tid = threadIdx.x;
  const float4* xr = (const float4*)(x + (size_t)row * 1024);
  float4 v = xr[tid];
  float s = v.x + v.y + v.z + v.w;
  float q = v.x * v.x + v.y * v.y + v.z * v.z + v.w * v.w;
#pragma unroll
  for (int m = 1; m < 64; m <<= 1) {
    s += __shfl_xor(s, m);
    q += __shfl_xor(q, m);
  }
  __shared__ float rs[4], rq[4];
  int w = tid >> 6;
  if ((tid & 63) == 0) { rs[w] = s; rq[w] = q; }
  __syncthreads();
  s = rs[0] + rs[1] + rs[2] + rs[3];
  q = rq[0] + rq[1] + rq[2] + rq[3];
  float mean = s * (1.0f / 1024.0f);
  float var = q * (1.0f / 1024.0f) - mean * mean;
  float inv = rsqrtf(var + 1e-5f);
  float4 g = ((const float4*)gamma)[tid];
  float4 bt = ((const float4*)beta)[tid];
  float4 o;
  o.x = (v.x - mean) * inv * g.x + bt.x;
  o.y = (v.y - mean) * inv * g.y + bt.y;
  o.z = (v.z - mean) * inv * g.z + bt.z;
  o.w = (v.w - mean) * inv * g.w + bt.w;
  ((float4*)(xn + (size_t)row * 1024))[tid] = o;
  ushort4 ob;
  ob.x = f2bf(o.x); ob.y = f2bf(o.y); ob.z = f2bf(o.z); ob.w = f2bf(o.w);
  ((ushort4*)(xnb + (size_t)row * 1024))[tid] = ob;
}

// ---------------- f32 -> bf16 convert: ctx (4096 blocks) + Ltab (tail blocks) ----------------
__global__ __launch_bounds__(256) void cvt2_kernel(const float* __restrict__ a,
                                                   u16* __restrict__ oa,
                                                   const float* __restrict__ bsrc,
                                                   u16* __restrict__ ob) {
  int blk = blockIdx.x;
  if (blk < 4096) {
    int i = blk * 256 + threadIdx.x;
    float4 v = ((const float4*)a)[i];
    ushort4 o;
    o.x = f2bf(v.x); o.y = f2bf(v.y); o.z = f2bf(v.z); o.w = f2bf(v.w);
    ((ushort4*)oa)[i] = o;
  } else {
    int i = (blk - 4096) * 256 + threadIdx.x;
    if (i < 65520) {
      float4 v = ((const float4*)bsrc)[i];
      ushort4 o;
      o.x = f2bf(v.x); o.y = f2bf(v.y); o.z = f2bf(v.z); o.w = f2bf(v.w);
      ((ushort4*)ob)[i] = o;
    }
  }
}

// ---------------- 4x W [1024,1024] f32 -> Wall[z] bf16 transposed (scaled) ----------------
__global__ __launch_bounds__(256) void transW_kernel(const float* __restrict__ W0,
                                                     const float* __restrict__ W1,
                                                     const float* __restrict__ W2,
                                                     const float* __restrict__ W3,
                                                     u16* __restrict__ Wall) {
  __shared__ float tile[32][33];
  int z = blockIdx.z;
  const float* W = (z == 0) ? W0 : (z == 1) ? W1 : (z == 2) ? W2 : W3;
  float scale = (z == 0) ? 0.18033688011112042f : (z == 1) ? 0.125f : 1.0f;
  u16* Wt = Wall + (size_t)z * 1048576;
  int tx = threadIdx.x, ty = threadIdx.y;
  int x = blockIdx.x * 32 + tx;
  int y0 = blockIdx.y * 32;
#pragma unroll
  for (int j = 0; j < 32; j += 8)
    tile[ty + j][tx] = W[(size_t)(y0 + ty + j) * 1024 + x];
  __syncthreads();
#pragma unroll
  for (int j = 0; j < 32; j += 8)
    Wt[(size_t)(blockIdx.x * 32 + ty + j) * 1024 + y0 + tx] = f2bf(tile[tx][ty + j] * scale);
}

// ---------------- shared GEMM core: 128x64 tile, K=1024, gload_lds + XOR swizzle ----------------
DEVFN void gemm_core(const u16* __restrict__ A, const u16* __restrict__ Bt,
                     u16* Ab, u16* Bb, int row0, int n0, int tid,
                     f32x4 (&acc)[2][4]) {
  int lane = tid & 63, wv = tid >> 6;
  int l16 = lane & 15, lhi = lane >> 4;
  int r8 = lane >> 3, c8 = lane & 7;
  int cx = ((c8 ^ r8) << 3);           // pre-swizzled source column (elements)
  int swz = (l16 & 7) << 3;            // read-side XOR (elements)

  auto stage = [&](int k0) {
#pragma unroll
    for (int i = 0; i < 4; ++i) {
      int rowb = wv * 32 + i * 8;
      gl16(&A[(size_t)(row0 + rowb + r8) * 1024 + k0 + cx], &Ab[rowb * 64]);
    }
#pragma unroll
    for (int i = 0; i < 2; ++i) {
      int rowb = wv * 16 + i * 8;
      gl16(&Bt[(size_t)(n0 + rowb + r8) * 1024 + k0 + cx], &Bb[rowb * 64]);
    }
  };

  stage(0);
  asm volatile("s_waitcnt vmcnt(0)" ::: "memory");
  __syncthreads();
  for (int kk = 0; kk < 16; ++kk) {
    __builtin_amdgcn_s_setprio(1);
#pragma unroll
    for (int ks = 0; ks < 2; ++ks) {
      bf16x8 af[2], bfr[4];
#pragma unroll
      for (int mi = 0; mi < 2; ++mi) {
        int row = wv * 32 + mi * 16 + l16;
        af[mi] = *(const bf16x8*)&Ab[row * 64 + ((ks * 32 + lhi * 8) ^ swz)];
      }
#pragma unroll
      for (int ni = 0; ni < 4; ++ni) {
        int row = ni * 16 + l16;
        bfr[ni] = *(const bf16x8*)&Bb[row * 64 + ((ks * 32 + lhi * 8) ^ swz)];
      }
#pragma unroll
      for (int mi = 0; mi < 2; ++mi)
#pragma unroll
        for (int ni = 0; ni < 4; ++ni)
          acc[mi][ni] = mfma16(af[mi], bfr[ni], acc[mi][ni]);
    }
    __builtin_amdgcn_s_setprio(0);
    if (kk < 15) {
      __syncthreads();
      stage((kk + 1) * 64);
      asm volatile("s_waitcnt vmcnt(0)" ::: "memory");
      __syncthreads();
    }
  }
}

// ---------------- QKV projections in one launch (z = 0,1,2) ----------------
// z=0: Q -> [B,H,T,64]; z=1: K -> [B,H,S,64]; z=2: V -> [B,H,64,S] transposed,
// with the in-tile key index pi-permuted: t' = (t&~63) | 4*(t&15) | ((t>>4)&3).
__global__ __launch_bounds__(256, 4) void qkv_kernel(const u16* __restrict__ xnb,
                                                     const u16* __restrict__ ctxb,
                                                     const u16* __restrict__ Wall,
                                                     u16* __restrict__ qb,
                                                     u16* __restrict__ kb,
                                                     u16* __restrict__ vtb) {
  __shared__ __align__(16) u16 Ab[128 * 64];
  __shared__ __align__(16) u16 Bb[64 * 64];
  int z = blockIdx.z;
  const u16* A = (z == 0) ? xnb : ctxb;
  const u16* Bt = Wall + (size_t)z * 1048576;
  int row0 = blockIdx.x * 128, n0 = blockIdx.y * 64;
  f32x4 acc[2][4] = {};
  gemm_core(A, Bt, Ab, Bb, row0, n0, threadIdx.x, acc);
  int tid = threadIdx.x, lane = tid & 63, wv = tid >> 6;
  int l16 = lane & 15, lhi = lane >> 4;
  u16* qk = (z == 0) ? qb : kb;
#pragma unroll
  for (int mi = 0; mi < 2; ++mi)
#pragma unroll
    for (int ni = 0; ni < 4; ++ni)
#pragma unroll
      for (int r = 0; r < 4; ++r) {
        int m = row0 + wv * 32 + mi * 16 + lhi * 4 + r;
        int n = n0 + ni * 16 + l16;
        int b = m >> 11, t = m & 2047, h = n >> 6, dh = n & 63;
        u16 val = f2bf(acc[mi][ni][r]);
        if (z < 2) {
          qk[(size_t)((b * 16 + h) * 2048 + t) * 64 + dh] = val;
        } else {
          int t2 = (t & ~63) | ((t & 15) << 2) | ((t >> 4) & 3);
          vtb[(size_t)((b * 16 + h) * 64 + dh) * 2048 + t2] = val;
        }
      }
}

// ---------------- output projection + bias + residual ----------------
__global__ __launch_bounds__(256, 4) void oproj_kernel(const u16* __restrict__ attnb,
                                                       const u16* __restrict__ Wall,
                                                       const float* __restrict__ bias,
                                                       const float* __restrict__ resid,
                                                       float* __restrict__ outF) {
  __shared__ __align__(16) u16 Ab[128 * 64];
  __shared__ __align__(16) u16 Bb[64 * 64];
  const u16* Bt = Wall + (size_t)3 * 1048576;
  int row0 = blockIdx.x * 128, n0 = blockIdx.y * 64;
  f32x4 acc[2][4] = {};
  gemm_core(attnb, Bt, Ab, Bb, row0, n0, threadIdx.x, acc);
  int tid = threadIdx.x, lane = tid & 63, wv = tid >> 6;
  int l16 = lane & 15, lhi = lane >> 4;
#pragma unroll
  for (int mi = 0; mi < 2; ++mi)
#pragma unroll
    for (int ni = 0; ni < 4; ++ni)
#pragma unroll
      for (int r = 0; r < 4; ++r) {
        int m = row0 + wv * 32 + mi * 16 + lhi * 4 + r;
        int n = n0 + ni * 16 + l16;
        outF[(size_t)m * 1024 + n] = acc[mi][ni][r] + bias[n] + resid[(size_t)m * 1024 + n];
      }
}

// ---------------- flash attention: 32 q-rows/wave, skewed pipeline ----------------
// 128 q-rows/block, grid 512 = exactly 2 blocks/CU (56KB LDS), 8 waves/CU.
// K/V/L B-fragments shared across the two 16-row m-tiles -> LDS reads/row halved.
// Band/wave = 95 positions -> accE[mt][6], carry blocks 4,5 -> 0,1 each tile.
// Union L = 192 rows. pi-packed P (one b64/row). Skewed r16 schedule.
__global__ __launch_bounds__(256, 2) void flash_kernel(
    const u16* __restrict__ Qg, const u16* __restrict__ Kg,
    const u16* __restrict__ Vtg, const u16* __restrict__ Lb,
    u16* __restrict__ Og) {
  constexpr int T = 2048, H = 16;
  int p = blockIdx.x;
  int bid = (p & 7) * 64 + (p >> 3);  // XCD-contiguous mapping (grid=512, 8 XCDs)
  int qb = bid & 15, h = (bid >> 4) & 15, b = bid >> 8;
  int tid = threadIdx.x;
  int lane = tid & 63, w = tid >> 6;
  int l16 = lane & 15, lhi = lane >> 4;

  __shared__ __align__(16) u16 Klds[64 * 64];      // 8 KB
  __shared__ __align__(16) u16 Vt[64 * 64];        // 8 KB
  __shared__ __align__(16) u16 Llds[192 * 64];     // 24 KB (union L band)
  __shared__ __align__(16) u16 Plds[4][32 * 64];   // 16 KB (XOR-swizzled, per-wave)

  const u16* qbase = Qg + (size_t)(b * H + h) * T * 64;
  const u16* kbase = Kg + (size_t)(b * H + h) * T * 64;
  const u16* vtbase = Vtg + (size_t)(b * H + h) * 64 * 2048;

  int i0b = qb * 128;
  int i0w = i0b + w * 32;
  bf16x8 aq[2][2];
#pragma unroll
  for (int mt = 0; mt < 2; ++mt)
#pragma unroll
    for (int ks = 0; ks < 2; ++ks)
      aq[mt][ks] = *(const bf16x8*)&qbase[(i0w + mt * 16 + l16) * 64 + ks * 32 + lhi * 8];

  f32x4 accO[2][4] = {};
  float mrun[2][4], lsum[2][4];
#pragma unroll
  for (int mt = 0; mt < 2; ++mt)
#pragma unroll
    for (int r = 0; r < 4; ++r) { mrun[mt][r] = -1e30f; lsum[mt][r] = 0.0f; }

  int bstart0 = T - 32 - i0w;   // tile-0 per-wave band start (>= 0)
  int ubase0 = T - 128 - i0b;   // union band start at j0=0 (>= 0)
  int uoff = 96 - 32 * w;       // wave's band pos 0 within the union tile

  int r8 = lane >> 3, c8 = lane & 7;
  int cx = ((c8 ^ r8) << 3);
  int swz = (l16 & 7) << 3;

  auto stageKL = [&](int j0) {
#pragma unroll
    for (int i = 0; i < 2; ++i) {
      int rowb = w * 16 + i * 8;
      gl16(&kbase[(size_t)(j0 + rowb + r8) * 64 + cx], &Klds[rowb * 64]);
    }
#pragma unroll
    for (int i = 0; i < 6; ++i) {
      int rowb = w * 48 + i * 8;
      gl16(&Lb[(size_t)(ubase0 + j0 + rowb + r8) * 64 + cx], &Llds[rowb * 64]);
    }
  };
  auto stageV = [&](int j0) {
#pragma unroll
    for (int i = 0; i < 2; ++i) {
      int rowb = w * 16 + i * 8;
      gl16(&vtbase[(size_t)(rowb + r8) * 2048 + j0 + cx], &Vt[rowb * 64]);
    }
  };

  // preamble: accE[mt][4],[5] hold E(tile-0 band positions 0..31); shifted in
  // by the first computeQKE. One-time scattered global reads (rows 0..2047).
  f32x4 accE[2][6];
#pragma unroll
  for (int mt = 0; mt < 2; ++mt)
#pragma unroll
    for (int c = 0; c < 6; ++c) accE[mt][c] = f32x4{0.f, 0.f, 0.f, 0.f};
#pragma unroll
  for (int ks = 0; ks < 2; ++ks)
#pragma unroll
    for (int c = 0; c < 2; ++c) {
      bf16x8 bl = *(const bf16x8*)&Lb[(size_t)(bstart0 + c * 16 + l16) * 64 + ks * 32 + lhi * 8];
      accE[0][4 + c] = mfma16(aq[0][ks], bl, accE[0][4 + c]);
      accE[1][4 + c] = mfma16(aq[1][ks], bl, accE[1][4 + c]);
    }

  f32x4 accS[2][4];
  auto computeQKE = [&]() {
#pragma unroll
    for (int mt = 0; mt < 2; ++mt) {
#pragma unroll
      for (int kb = 0; kb < 4; ++kb) accS[mt][kb] = f32x4{0.f, 0.f, 0.f, 0.f};
      accE[mt][0] = accE[mt][4];
      accE[mt][1] = accE[mt][5];
#pragma unroll
      for (int c = 2; c < 6; ++c) accE[mt][c] = f32x4{0.f, 0.f, 0.f, 0.f};
    }
    __builtin_amdgcn_s_setprio(1);
#pragma unroll
    for (int ks = 0; ks < 2; ++ks) {
#pragma unroll
      for (int kb = 0; kb < 4; ++kb) {
        bf16x8 bk = *(const bf16x8*)&Klds[(kb * 16 + l16) * 64 + ((ks * 32 + lhi * 8) ^ swz)];
        accS[0][kb] = mfma16(aq[0][ks], bk, accS[0][kb]);
        accS[1][kb] = mfma16(aq[1][ks], bk, accS[1][kb]);
      }
#pragma unroll
      for (int c = 2; c < 6; ++c) {
        int urow = uoff + c * 16 + l16;
        bf16x8 bl = *(const bf16x8*)&Llds[urow * 64 + ((ks * 32 + lhi * 8) ^ swz)];
        accE[0][c] = mfma16(aq[0][ks], bl, accE[0][c]);
        accE[1][c] = mfma16(aq[1][ks], bl, accE[1][c]);
      }
    }
    __builtin_amdgcn_s_setprio(0);
  };

  const float THR = 11.541560327111707f;  // 8 * log2(e)

  // prologue
  stageKL(0);
  asm volatile("s_waitcnt vmcnt(0)" ::: "memory");
  __syncthreads();
  stageV(0);
  computeQKE();

  for (int kt = 0; kt < 32; ++kt) {
    __syncthreads();  // sync_A: drains V(kt) (covered by QK/E); K/L buffers free
    if (kt < 31) stageKL((kt + 1) * 64);
    __builtin_amdgcn_sched_barrier(0);  // pin stage issue before softmax

    // softmax(kt); E gathered via in-wave shuffles (srcl shared across mt)
    float sc[2][4][4];
    float lm[2][4];
    bool need = false;
#pragma unroll
    for (int r = 0; r < 4; ++r) {
      int srcl = lhi * 16 + ((l16 - lhi * 4 - r + 15) & 15);
      bool lo = (l16 <= lhi * 4 + r);
      float e0[5], e1[5];
#pragma unroll
      for (int c = 0; c < 5; ++c) {
        e0[c] = __shfl(accE[0][c + 1][r], srcl);  // mt=0 needs blocks 1..5
        e1[c] = __shfl(accE[1][c][r], srcl);      // mt=1 needs blocks 0..4
      }
#pragma unroll
      for (int kb = 0; kb < 4; ++kb) {
        sc[0][r][kb] = accS[0][kb][r] + (lo ? e0[kb] : e0[kb + 1]);
        sc[1][r][kb] = accS[1][kb][r] + (lo ? e1[kb] : e1[kb + 1]);
      }
#pragma unroll
      for (int mt = 0; mt < 2; ++mt) {
        lm[mt][r] = fmaxf(fmaxf(sc[mt][r][0], sc[mt][r][1]),
                          fmaxf(sc[mt][r][2], sc[mt][r][3]));
        need |= (lm[mt][r] > mrun[mt][r] + THR);
      }
    }
    // lazy max: full tree + rescale only when triggered
    if (__ballot(need)) {
#pragma unroll
      for (int mt = 0; mt < 2; ++mt)
#pragma unroll
        for (int r = 0; r < 4; ++r) {
          float tm = lm[mt][r];
          tm = fmaxf(tm, __shfl_xor(tm, 1));
          tm = fmaxf(tm, __shfl_xor(tm, 2));
          tm = fmaxf(tm, __shfl_xor(tm, 4));
          tm = fmaxf(tm, __shfl_xor(tm, 8));
          float mnew = fmaxf(mrun[mt][r], tm);
          float al = exp2f(mrun[mt][r] - mnew);
          mrun[mt][r] = mnew;
          lsum[mt][r] *= al;
#pragma unroll
          for (int dt = 0; dt < 4; ++dt) accO[mt][dt][r] *= al;
        }
    }
#pragma unroll
    for (int r = 0; r < 4; ++r)
#pragma unroll
      for (int mt = 0; mt < 2; ++mt) {
        int row = mt * 16 + lhi * 4 + r;
        float mm = mrun[mt][r];
        float pv0 = exp2f(sc[mt][r][0] - mm);
        float pv1 = exp2f(sc[mt][r][1] - mm);
        float pv2 = exp2f(sc[mt][r][2] - mm);
        float pv3 = exp2f(sc[mt][r][3] - mm);
        lsum[mt][r] += (pv0 + pv1) + (pv2 + pv3);
        unsigned pk01, pk23;
        asm("v_cvt_pk_bf16_f32 %0, %1, %2" : "=v"(pk01) : "v"(pv0), "v"(pv1));
        asm("v_cvt_pk_bf16_f32 %0, %1, %2" : "=v"(pk23) : "v"(pv2), "v"(pv3));
        uint2 pw;
        pw.x = pk01;
        pw.y = pk23;
        *(uint2*)&Plds[w][row * 64 + ((l16 * 4) ^ ((row & 7) << 3))] = pw;
      }

    // PV(kt): accO[mt][dt] += P[mt] @ V (V B-frags shared across mt)
    __builtin_amdgcn_s_setprio(1);
#pragma unroll
    for (int ks = 0; ks < 2; ++ks) {
      bf16x8 ap0 = *(const bf16x8*)&Plds[w][(l16) * 64 + ((ks * 32 + lhi * 8) ^ swz)];
      bf16x8 ap1 = *(const bf16x8*)&Plds[w][(16 + l16) * 64 + ((ks * 32 + lhi * 8) ^ swz)];
#pragma unroll
      for (int dt = 0; dt < 4; ++dt) {
        bf16x8 bv = *(const bf16x8*)&Vt[(dt * 16 + l16) * 64 + ((ks * 32 + lhi * 8) ^ swz)];
        accO[0][dt] = mfma16(ap0, bv, accO[0][dt]);
        accO[1][dt] = mfma16(ap1, bv, accO[1][dt]);
      }
    }
    __builtin_amdgcn_s_setprio(0);

    __syncthreads();  // sync_B: drains K/L(kt+1) (covered by softmax+PV); V free
    if (kt < 31) {
      stageV((kt + 1) * 64);
      __builtin_amdgcn_sched_barrier(0);  // pin V issue before QK/E
      computeQKE();  // QK/E(kt+1); covers V(kt+1) drain at next sync_A
    }
  }

  // epilogue: reduce l across the 16-lane row groups, then O *= 1/l
#pragma unroll
  for (int mt = 0; mt < 2; ++mt)
#pragma unroll
    for (int r = 0; r < 4; ++r) {
      float l = lsum[mt][r];
      l += __shfl_xor(l, 1);
      l += __shfl_xor(l, 2);
      l += __shfl_xor(l, 4);
      l += __shfl_xor(l, 8);
      lsum[mt][r] = 1.0f / l;
    }
#pragma unroll
  for (int mt = 0; mt < 2; ++mt)
#pragma unroll
    for (int dt = 0; dt < 4; ++dt)
#pragma unroll
      for (int r = 0; r < 4; ++r) {
        int i = i0w + mt * 16 + lhi * 4 + r;
        int col = h * 64 + dt * 16 + l16;
        Og[(size_t)(b * T + i) * 1024 + col] = f2bf(accO[mt][dt][r] * lsum[mt][r]);
      }
}

extern "C" void kernel_launch(void* const* d_in, const int* in_sizes, int n_in,
                              void* d_out, int out_size, void* d_ws, size_t ws_size,
                              hipStream_t stream) {
  const float* x = (const float*)d_in[0];
  const float* ctx = (const float*)d_in[1];
  const float* Ltab = (const float*)d_in[2];
  const float* Wq = (const float*)d_in[3];
  const float* Wk = (const float*)d_in[4];
  const float* Wv = (const float*)d_in[5];
  const float* Wo = (const float*)d_in[6];
  const float* bo = (const float*)d_in[7];
  const float* gamma = (const float*)d_in[8];
  const float* beta = (const float*)d_in[9];
  float* out = (float*)d_out;

  size_t off = 0;
  auto take = [&](size_t bytes) {
    void* p = (char*)d_ws + off;
    off += (bytes + 255) & ~(size_t)255;
    return p;
  };
  u16* xnb = (u16*)take(8388608);    // xn bf16 [4096,1024]
  u16* ctxb = (u16*)take(8388608);   // context bf16
  u16* Lb = (u16*)take(4095 * 64 * 2);  // +128B pad absorbs union-row-4095 read
  u16* Wall = (u16*)take(4 * 2097152);  // Wq',Wk',Wv,Wo transposed bf16
  u16* qbuf = (u16*)take(8388608);   // [B,H,T,64]
  u16* kbuf = (u16*)take(8388608);   // [B,H,S,64]
  u16* vtbuf = (u16*)take(8388608);  // [B,H,64,S] (pi-permuted keys)
  u16* attnb = (u16*)take(8388608);  // [B*T, 1024]

  ln_kernel<<<dim3(4096), dim3(256), 0, stream>>>(x, gamma, beta, out, xnb);
  cvt2_kernel<<<dim3(4096 + 256), dim3(256), 0, stream>>>(ctx, ctxb, Ltab, Lb);
  transW_kernel<<<dim3(32, 32, 4), dim3(32, 8), 0, stream>>>(Wq, Wk, Wv, Wo, Wall);
  qkv_kernel<<<dim3(32, 16, 3), dim3(256), 0, stream>>>(xnb, ctxb, Wall, qbuf, kbuf, vtbuf);
  flash_kernel<<<dim3(512), dim3(256), 0, stream>>>(qbuf, kbuf, vtbuf, Lb, attnb);
  oproj_kernel<<<dim3(32, 16), dim3(256), 0, stream>>>(attnb, Wall, bo, out, out);
}

// Round 19
// 190.744 us; speedup vs baseline: 1.0317x; 1.0317x over previous
//
#include <hip/hip_runtime.h>

#define DEVFN __device__ __forceinline__

typedef __bf16 bf16x8 __attribute__((ext_vector_type(8)));
typedef float f32x4 __attribute__((ext_vector_type(4)));
typedef unsigned short u16;

// B=2, T=S=2048, D=1024, H=16, DH=64
// Scales folded into weights: Wq *= 0.125*log2(e), Wk *= 0.125  =>
// score_log2e = q'.k' + q'.L  ; softmax done in exp2 domain.
// Key axis of P and V permuted per 64-key tile by pi(k) = 4*(k&15) + (k>>4).

DEVFN u16 f2bf(float f) {
  unsigned u = __builtin_bit_cast(unsigned, f);
  u += 0x7FFFu + ((u >> 16) & 1u);
  return (u16)(u >> 16);
}

DEVFN float bfbits(unsigned hi) {  // bf16 in high 16 bits -> f32
  return __builtin_bit_cast(float, hi);
}

DEVFN f32x4 mfma16(bf16x8 a, bf16x8 b, f32x4 c) {
  return __builtin_amdgcn_mfma_f32_16x16x32_bf16(a, b, c, 0, 0, 0);
}

DEVFN void gl16(const u16* g, u16* l) {
  __builtin_amdgcn_global_load_lds(
      (const __attribute__((address_space(1))) unsigned int*)g,
      (__attribute__((address_space(3))) unsigned int*)l, 16, 0, 0);
}

// ---------------- LayerNorm: x[4096,1024] -> xn (f32, into d_out) + xn bf16 ----------------
__global__ __launch_bounds__(256) void ln_kernel(const float* __restrict__ x,
                                                 const float* __restrict__ gamma,
                                                 const float* __restrict__ beta,
                                                 float* __restrict__ xn,
                                                 u16* __restrict__ xnb) {
  int row = blockIdx.x;
  int tid = threadIdx.x;
  const float4* xr = (const float4*)(x + (size_t)row * 1024);
  float4 v = xr[tid];
  float s = v.x + v.y + v.z + v.w;
  float q = v.x * v.x + v.y * v.y + v.z * v.z + v.w * v.w;
#pragma unroll
  for (int m = 1; m < 64; m <<= 1) {
    s += __shfl_xor(s, m);
    q += __shfl_xor(q, m);
  }
  __shared__ float rs[4], rq[4];
  int w = tid >> 6;
  if ((tid & 63) == 0) { rs[w] = s; rq[w] = q; }
  __syncthreads();
  s = rs[0] + rs[1] + rs[2] + rs[3];
  q = rq[0] + rq[1] + rq[2] + rq[3];
  float mean = s * (1.0f / 1024.0f);
  float var = q * (1.0f / 1024.0f) - mean * mean;
  float inv = rsqrtf(var + 1e-5f);
  float4 g = ((const float4*)gamma)[tid];
  float4 bt = ((const float4*)beta)[tid];
  float4 o;
  o.x = (v.x - mean) * inv * g.x + bt.x;
  o.y = (v.y - mean) * inv * g.y + bt.y;
  o.z = (v.z - mean) * inv * g.z + bt.z;
  o.w = (v.w - mean) * inv * g.w + bt.w;
  ((float4*)(xn + (size_t)row * 1024))[tid] = o;
  ushort4 ob;
  ob.x = f2bf(o.x); ob.y = f2bf(o.y); ob.z = f2bf(o.z); ob.w = f2bf(o.w);
  ((ushort4*)(xnb + (size_t)row * 1024))[tid] = ob;
}

// ---------------- f32 -> bf16 convert: ctx (4096 blocks) + Ltab (tail blocks) ----------------
__global__ __launch_bounds__(256) void cvt2_kernel(const float* __restrict__ a,
                                                   u16* __restrict__ oa,
                                                   const float* __restrict__ bsrc,
                                                   u16* __restrict__ ob) {
  int blk = blockIdx.x;
  if (blk < 4096) {
    int i = blk * 256 + threadIdx.x;
    float4 v = ((const float4*)a)[i];
    ushort4 o;
    o.x = f2bf(v.x); o.y = f2bf(v.y); o.z = f2bf(v.z); o.w = f2bf(v.w);
    ((ushort4*)oa)[i] = o;
  } else {
    int i = (blk - 4096) * 256 + threadIdx.x;
    if (i < 65520) {
      float4 v = ((const float4*)bsrc)[i];
      ushort4 o;
      o.x = f2bf(v.x); o.y = f2bf(v.y); o.z = f2bf(v.z); o.w = f2bf(v.w);
      ((ushort4*)ob)[i] = o;
    }
  }
}

// ---------------- 4x W [1024,1024] f32 -> Wall[z] bf16 transposed (scaled) ----------------
__global__ __launch_bounds__(256) void transW_kernel(const float* __restrict__ W0,
                                                     const float* __restrict__ W1,
                                                     const float* __restrict__ W2,
                                                     const float* __restrict__ W3,
                                                     u16* __restrict__ Wall) {
  __shared__ float tile[32][33];
  int z = blockIdx.z;
  const float* W = (z == 0) ? W0 : (z == 1) ? W1 : (z == 2) ? W2 : W3;
  float scale = (z == 0) ? 0.18033688011112042f : (z == 1) ? 0.125f : 1.0f;
  u16* Wt = Wall + (size_t)z * 1048576;
  int tx = threadIdx.x, ty = threadIdx.y;
  int x = blockIdx.x * 32 + tx;
  int y0 = blockIdx.y * 32;
#pragma unroll
  for (int j = 0; j < 32; j += 8)
    tile[ty + j][tx] = W[(size_t)(y0 + ty + j) * 1024 + x];
  __syncthreads();
#pragma unroll
  for (int j = 0; j < 32; j += 8)
    Wt[(size_t)(blockIdx.x * 32 + ty + j) * 1024 + y0 + tx] = f2bf(tile[tx][ty + j] * scale);
}

// ---------------- shared GEMM core: 128x64 tile, K=1024, gload_lds + XOR swizzle ----------------
DEVFN void gemm_core(const u16* __restrict__ A, const u16* __restrict__ Bt,
                     u16* Ab, u16* Bb, int row0, int n0, int tid,
                     f32x4 (&acc)[2][4]) {
  int lane = tid & 63, wv = tid >> 6;
  int l16 = lane & 15, lhi = lane >> 4;
  int r8 = lane >> 3, c8 = lane & 7;
  int cx = ((c8 ^ r8) << 3);           // pre-swizzled source column (elements)
  int swz = (l16 & 7) << 3;            // read-side XOR (elements)

  auto stage = [&](int k0) {
#pragma unroll
    for (int i = 0; i < 4; ++i) {
      int rowb = wv * 32 + i * 8;
      gl16(&A[(size_t)(row0 + rowb + r8) * 1024 + k0 + cx], &Ab[rowb * 64]);
    }
#pragma unroll
    for (int i = 0; i < 2; ++i) {
      int rowb = wv * 16 + i * 8;
      gl16(&Bt[(size_t)(n0 + rowb + r8) * 1024 + k0 + cx], &Bb[rowb * 64]);
    }
  };

  stage(0);
  asm volatile("s_waitcnt vmcnt(0)" ::: "memory");
  __syncthreads();
  for (int kk = 0; kk < 16; ++kk) {
    __builtin_amdgcn_s_setprio(1);
#pragma unroll
    for (int ks = 0; ks < 2; ++ks) {
      bf16x8 af[2], bfr[4];
#pragma unroll
      for (int mi = 0; mi < 2; ++mi) {
        int row = wv * 32 + mi * 16 + l16;
        af[mi] = *(const bf16x8*)&Ab[row * 64 + ((ks * 32 + lhi * 8) ^ swz)];
      }
#pragma unroll
      for (int ni = 0; ni < 4; ++ni) {
        int row = ni * 16 + l16;
        bfr[ni] = *(const bf16x8*)&Bb[row * 64 + ((ks * 32 + lhi * 8) ^ swz)];
      }
#pragma unroll
      for (int mi = 0; mi < 2; ++mi)
#pragma unroll
        for (int ni = 0; ni < 4; ++ni)
          acc[mi][ni] = mfma16(af[mi], bfr[ni], acc[mi][ni]);
    }
    __builtin_amdgcn_s_setprio(0);
    if (kk < 15) {
      __syncthreads();
      stage((kk + 1) * 64);
      asm volatile("s_waitcnt vmcnt(0)" ::: "memory");
      __syncthreads();
    }
  }
}

// ---------------- QKV projections in one launch (z = 0,1,2) ----------------
// z=0: Q -> [B,H,T,64]; z=1: K -> [B,H,S,64]; z=2: V -> [B,H,64,S] transposed,
// with the in-tile key index pi-permuted: t' = (t&~63) | 4*(t&15) | ((t>>4)&3).
__global__ __launch_bounds__(256, 4) void qkv_kernel(const u16* __restrict__ xnb,
                                                     const u16* __restrict__ ctxb,
                                                     const u16* __restrict__ Wall,
                                                     u16* __restrict__ qb,
                                                     u16* __restrict__ kb,
                                                     u16* __restrict__ vtb) {
  __shared__ __align__(16) u16 Ab[128 * 64];
  __shared__ __align__(16) u16 Bb[64 * 64];
  int z = blockIdx.z;
  const u16* A = (z == 0) ? xnb : ctxb;
  const u16* Bt = Wall + (size_t)z * 1048576;
  int row0 = blockIdx.x * 128, n0 = blockIdx.y * 64;
  f32x4 acc[2][4] = {};
  gemm_core(A, Bt, Ab, Bb, row0, n0, threadIdx.x, acc);
  int tid = threadIdx.x, lane = tid & 63, wv = tid >> 6;
  int l16 = lane & 15, lhi = lane >> 4;
  u16* qk = (z == 0) ? qb : kb;
#pragma unroll
  for (int mi = 0; mi < 2; ++mi)
#pragma unroll
    for (int ni = 0; ni < 4; ++ni)
#pragma unroll
      for (int r = 0; r < 4; ++r) {
        int m = row0 + wv * 32 + mi * 16 + lhi * 4 + r;
        int n = n0 + ni * 16 + l16;
        int b = m >> 11, t = m & 2047, h = n >> 6, dh = n & 63;
        u16 val = f2bf(acc[mi][ni][r]);
        if (z < 2) {
          qk[(size_t)((b * 16 + h) * 2048 + t) * 64 + dh] = val;
        } else {
          int t2 = (t & ~63) | ((t & 15) << 2) | ((t >> 4) & 3);
          vtb[(size_t)((b * 16 + h) * 64 + dh) * 2048 + t2] = val;
        }
      }
}

// ---------------- output projection + bias + residual ----------------
__global__ __launch_bounds__(256, 4) void oproj_kernel(const u16* __restrict__ attnb,
                                                       const u16* __restrict__ Wall,
                                                       const float* __restrict__ bias,
                                                       const float* __restrict__ resid,
                                                       float* __restrict__ outF) {
  __shared__ __align__(16) u16 Ab[128 * 64];
  __shared__ __align__(16) u16 Bb[64 * 64];
  const u16* Bt = Wall + (size_t)3 * 1048576;
  int row0 = blockIdx.x * 128, n0 = blockIdx.y * 64;
  f32x4 acc[2][4] = {};
  gemm_core(attnb, Bt, Ab, Bb, row0, n0, threadIdx.x, acc);
  int tid = threadIdx.x, lane = tid & 63, wv = tid >> 6;
  int l16 = lane & 15, lhi = lane >> 4;
#pragma unroll
  for (int mi = 0; mi < 2; ++mi)
#pragma unroll
    for (int ni = 0; ni < 4; ++ni)
#pragma unroll
      for (int r = 0; r < 4; ++r) {
        int m = row0 + wv * 32 + mi * 16 + lhi * 4 + r;
        int n = n0 + ni * 16 + l16;
        outF[(size_t)m * 1024 + n] = acc[mi][ni][r] + bias[n] + resid[(size_t)m * 1024 + n];
      }
}

// ---------------- flash attention: skewed pipeline, rolling L, packed e-gather ----------------
// r17 structure (16 q-rows/wave, grid 1024, 4 blocks/CU). Changes:
// (1) rolling 128-row L buffer: consecutive bands overlap 64 rows, so only the
//     64 NEW rows are staged per iter (phys row = ((half_log + t)&1)*64 | row&63).
// (2) e-gather packed to bf16 pairs before shuffle: 3 shuffles/row instead of 5.
__global__ __launch_bounds__(256, 4) void flash_kernel(
    const u16* __restrict__ Qg, const u16* __restrict__ Kg,
    const u16* __restrict__ Vtg, const u16* __restrict__ Lb,
    u16* __restrict__ Og) {
  constexpr int T = 2048, H = 16;
  int p = blockIdx.x;
  int bid = (p & 7) * 128 + (p >> 3);  // XCD-contiguous mapping (grid=1024, 8 XCDs)
  int qb = bid & 31, h = (bid >> 5) & 15, b = bid >> 9;
  int tid = threadIdx.x;
  int lane = tid & 63, w = tid >> 6;
  int l16 = lane & 15, lhi = lane >> 4;

  __shared__ __align__(16) u16 Klds[64 * 64];      // 8 KB
  __shared__ __align__(16) u16 Vt[64 * 64];        // 8 KB
  __shared__ __align__(16) u16 Llds[128 * 64];     // 16 KB rolling (2 halves)
  __shared__ __align__(16) u16 Plds[4][16 * 64];   // 8 KB (pi-packed, per-wave)

  const u16* qbase = Qg + (size_t)(b * H + h) * T * 64;
  const u16* kbase = Kg + (size_t)(b * H + h) * T * 64;
  const u16* vtbase = Vtg + (size_t)(b * H + h) * 64 * 2048;

  int i0b = qb * 64;
  int i0w = i0b + w * 16;
  bf16x8 aq[2];
  aq[0] = *(const bf16x8*)&qbase[(i0w + l16) * 64 + lhi * 8];
  aq[1] = *(const bf16x8*)&qbase[(i0w + l16) * 64 + 32 + lhi * 8];

  f32x4 accO[4] = {};
  float mrun[4], lsum[4];
#pragma unroll
  for (int r = 0; r < 4; ++r) { mrun[r] = -1e30f; lsum[r] = 0.0f; }

  int bandbase = T - 16 - i0w;   // per-wave band start (>= 0 always)
  int ubase0 = T - 64 - i0b;     // union band start at j0=0 (multiple of 64)
  int uoff = 48 - 16 * w;        // wave's band col 0 within the union tile

  int r8 = lane >> 3, c8 = lane & 7;
  int cx = ((c8 ^ r8) << 3);
  int swz = (l16 & 7) << 3;

  auto stageK = [&](int j0) {
#pragma unroll
    for (int i = 0; i < 2; ++i) {
      int rowb = w * 16 + i * 8;
      gl16(&kbase[(size_t)(j0 + rowb + r8) * 64 + cx], &Klds[rowb * 64]);
    }
  };
  // in-loop: stage the 64 NEW L rows for tile (kt+1) into phys half (kt&1)
  auto stageLnew = [&](int kt) {
#pragma unroll
    for (int i = 0; i < 2; ++i) {
      int rowb = w * 16 + i * 8;  // 0..63 over the block
      gl16(&Lb[(size_t)(ubase0 + kt * 64 + 128 + rowb + r8) * 64 + cx],
           &Llds[((kt & 1) * 64 + rowb) * 64]);
    }
  };
  auto stageV = [&](int j0) {
#pragma unroll
    for (int i = 0; i < 2; ++i) {
      int rowb = w * 16 + i * 8;
      gl16(&vtbase[(size_t)(rowb + r8) * 2048 + j0 + cx], &Vt[rowb * 64]);
    }
  };

  // E-carry preamble: eC = E[., band cols 0..15] of tile 0 (global, one-time)
  const u16* lp = Lb + (size_t)(bandbase + l16) * 64 + lhi * 8;
  f32x4 eC = {};
#pragma unroll
  for (int ks = 0; ks < 2; ++ks)
    eC = mfma16(aq[ks], *(const bf16x8*)&lp[ks * 32], eC);

  f32x4 accS[4];
  f32x4 accE[5];
  auto computeQKE = [&](int tb) {  // tb = tile parity (kt & 1)
#pragma unroll
    for (int kb = 0; kb < 4; ++kb) accS[kb] = f32x4{0.f, 0.f, 0.f, 0.f};
    accE[0] = eC;
#pragma unroll
    for (int c = 1; c < 5; ++c) accE[c] = f32x4{0.f, 0.f, 0.f, 0.f};
    __builtin_amdgcn_s_setprio(1);
#pragma unroll
    for (int ks = 0; ks < 2; ++ks) {
#pragma unroll
      for (int kb = 0; kb < 4; ++kb) {
        int row = kb * 16 + l16;
        bf16x8 bk = *(const bf16x8*)&Klds[row * 64 + ((ks * 32 + lhi * 8) ^ swz)];
        accS[kb] = mfma16(aq[ks], bk, accS[kb]);
      }
#pragma unroll
      for (int c = 1; c < 5; ++c) {
        int ulog = uoff + c * 16;                       // 16-aligned, in [16,112]
        int prow = ((((ulog >> 6) + tb) & 1) << 6) | ((ulog & 63) + l16);
        bf16x8 bl = *(const bf16x8*)&Llds[prow * 64 + ((ks * 32 + lhi * 8) ^ swz)];
        accE[c] = mfma16(aq[ks], bl, accE[c]);
      }
    }
    __builtin_amdgcn_s_setprio(0);
    eC = accE[4];
  };

  const float THR = 11.541560327111707f;  // 8 * log2(e)

  // prologue: tile 0 (K + both L halves) staged + QK/E(0)
  stageK(0);
#pragma unroll
  for (int i = 0; i < 4; ++i) {
    int rowb = w * 32 + i * 8;
    gl16(&Lb[(size_t)(ubase0 + rowb + r8) * 64 + cx], &Llds[rowb * 64]);
  }
  asm volatile("s_waitcnt vmcnt(0)" ::: "memory");
  __syncthreads();
  stageV(0);
  computeQKE(0);

  for (int kt = 0; kt < 32; ++kt) {
    __syncthreads();  // sync_A: drains V(kt) (covered by QK/E); K + old-L free
    if (kt < 31) {
      stageK((kt + 1) * 64);
      stageLnew(kt);
    }
    __builtin_amdgcn_sched_barrier(0);  // pin stage issue before softmax

    // softmax(kt); e-gather via bf16-packed shuffles (3 per row)
    float sc[4][4];
    float lm[4];
    bool need = false;
#pragma unroll
    for (int r = 0; r < 4; ++r) {
      int m = lhi * 4 + r;
      int srcl = lhi * 16 + ((l16 - m + 15) & 15);
      bool lo = (l16 <= m);
      unsigned q01, q23;
      asm("v_cvt_pk_bf16_f32 %0, %1, %2" : "=v"(q01) : "v"(accE[0][r]), "v"(accE[1][r]));
      asm("v_cvt_pk_bf16_f32 %0, %1, %2" : "=v"(q23) : "v"(accE[2][r]), "v"(accE[3][r]));
      q01 = (unsigned)__shfl((int)q01, srcl);
      q23 = (unsigned)__shfl((int)q23, srcl);
      float e4 = __shfl(accE[4][r], srcl);
      float e0 = bfbits(q01 << 16), e1 = bfbits(q01 & 0xffff0000u);
      float e2 = bfbits(q23 << 16), e3 = bfbits(q23 & 0xffff0000u);
      sc[r][0] = accS[0][r] + (lo ? e0 : e1);
      sc[r][1] = accS[1][r] + (lo ? e1 : e2);
      sc[r][2] = accS[2][r] + (lo ? e2 : e3);
      sc[r][3] = accS[3][r] + (lo ? e3 : e4);
      lm[r] = fmaxf(fmaxf(sc[r][0], sc[r][1]), fmaxf(sc[r][2], sc[r][3]));
      need |= (lm[r] > mrun[r] + THR);
    }
    // lazy max: full tree + rescale only when some lane's local max exceeds THR
    if (__ballot(need)) {
#pragma unroll
      for (int r = 0; r < 4; ++r) {
        float tm = lm[r];
        tm = fmaxf(tm, __shfl_xor(tm, 1));
        tm = fmaxf(tm, __shfl_xor(tm, 2));
        tm = fmaxf(tm, __shfl_xor(tm, 4));
        tm = fmaxf(tm, __shfl_xor(tm, 8));
        float mnew = fmaxf(mrun[r], tm);
        float al = exp2f(mrun[r] - mnew);
        mrun[r] = mnew;
        lsum[r] *= al;
#pragma unroll
        for (int dt = 0; dt < 4; ++dt) accO[dt][r] *= al;
      }
    }
#pragma unroll
    for (int r = 0; r < 4; ++r) {
      int m = lhi * 4 + r;
      float mm = mrun[r];
      float pv0 = exp2f(sc[r][0] - mm);
      float pv1 = exp2f(sc[r][1] - mm);
      float pv2 = exp2f(sc[r][2] - mm);
      float pv3 = exp2f(sc[r][3] - mm);
      lsum[r] += (pv0 + pv1) + (pv2 + pv3);
      unsigned pk01, pk23;
      asm("v_cvt_pk_bf16_f32 %0, %1, %2" : "=v"(pk01) : "v"(pv0), "v"(pv1));
      asm("v_cvt_pk_bf16_f32 %0, %1, %2" : "=v"(pk23) : "v"(pv2), "v"(pv3));
      // keys kb*16+l16 -> pi-slots 4*l16+kb: one b64 covers all four
      uint2 pw;
      pw.x = pk01;
      pw.y = pk23;
      *(uint2*)&Plds[w][m * 64 + ((l16 * 4) ^ ((m & 7) << 3))] = pw;
    }

    // PV(kt): accO[dt] += P[16,64] @ V[64, dt*16..] (pi-slot k-dimension)
    __builtin_amdgcn_s_setprio(1);
#pragma unroll
    for (int ks = 0; ks < 2; ++ks) {
      bf16x8 ap = *(const bf16x8*)&Plds[w][l16 * 64 + ((ks * 32 + lhi * 8) ^ swz)];
#pragma unroll
      for (int dt = 0; dt < 4; ++dt) {
        int row = dt * 16 + l16;
        bf16x8 bv = *(const bf16x8*)&Vt[row * 64 + ((ks * 32 + lhi * 8) ^ swz)];
        accO[dt] = mfma16(ap, bv, accO[dt]);
      }
    }
    __builtin_amdgcn_s_setprio(0);

    __syncthreads();  // sync_B: drains K/L(kt+1) (covered by softmax+PV); V free
    if (kt < 31) {
      stageV((kt + 1) * 64);
      __builtin_amdgcn_sched_barrier(0);  // pin V issue before QK/E
      computeQKE((kt + 1) & 1);  // QK/E(kt+1); covers V(kt+1) drain at next sync_A
    }
  }

  // epilogue: reduce l across the 16-lane row groups, then O *= 1/l
#pragma unroll
  for (int r = 0; r < 4; ++r) {
    float l = lsum[r];
    l += __shfl_xor(l, 1);
    l += __shfl_xor(l, 2);
    l += __shfl_xor(l, 4);
    l += __shfl_xor(l, 8);
    lsum[r] = 1.0f / l;
  }
#pragma unroll
  for (int dt = 0; dt < 4; ++dt)
#pragma unroll
    for (int r = 0; r < 4; ++r) {
      int i = i0w + lhi * 4 + r;
      int col = h * 64 + dt * 16 + l16;
      Og[(size_t)(b * T + i) * 1024 + col] = f2bf(accO[dt][r] * lsum[r]);
    }
}

extern "C" void kernel_launch(void* const* d_in, const int* in_sizes, int n_in,
                              void* d_out, int out_size, void* d_ws, size_t ws_size,
                              hipStream_t stream) {
  const float* x = (const float*)d_in[0];
  const float* ctx = (const float*)d_in[1];
  const float* Ltab = (const float*)d_in[2];
  const float* Wq = (const float*)d_in[3];
  const float* Wk = (const float*)d_in[4];
  const float* Wv = (const float*)d_in[5];
  const float* Wo = (const float*)d_in[6];
  const float* bo = (const float*)d_in[7];
  const float* gamma = (const float*)d_in[8];
  const float* beta = (const float*)d_in[9];
  float* out = (float*)d_out;

  size_t off = 0;
  auto take = [&](size_t bytes) {
    void* p = (char*)d_ws + off;
    off += (bytes + 255) & ~(size_t)255;
    return p;
  };
  u16* xnb = (u16*)take(8388608);    // xn bf16 [4096,1024]
  u16* ctxb = (u16*)take(8388608);   // context bf16
  u16* Lb = (u16*)take(4095 * 64 * 2);  // pad absorbs any tail staging overread
  u16* Wall = (u16*)take(4 * 2097152);  // Wq',Wk',Wv,Wo transposed bf16
  u16* qbuf = (u16*)take(8388608);   // [B,H,T,64]
  u16* kbuf = (u16*)take(8388608);   // [B,H,S,64]
  u16* vtbuf = (u16*)take(8388608);  // [B,H,64,S] (pi-permuted keys)
  u16* attnb = (u16*)take(8388608);  // [B*T, 1024]

  ln_kernel<<<dim3(4096), dim3(256), 0, stream>>>(x, gamma, beta, out, xnb);
  cvt2_kernel<<<dim3(4096 + 256), dim3(256), 0, stream>>>(ctx, ctxb, Ltab, Lb);
  transW_kernel<<<dim3(32, 32, 4), dim3(32, 8), 0, stream>>>(Wq, Wk, Wv, Wo, Wall);
  qkv_kernel<<<dim3(32, 16, 3), dim3(256), 0, stream>>>(xnb, ctxb, Wall, qbuf, kbuf, vtbuf);
  flash_kernel<<<dim3(1024), dim3(256), 0, stream>>>(qbuf, kbuf, vtbuf, Lb, attnb);
  oproj_kernel<<<dim3(32, 16), dim3(256), 0, stream>>>(attnb, Wall, bo, out, out);
}